// Round 8
// baseline (263.770 us; speedup 1.0000x reference)
//
#include <hip/hip_runtime.h>
#include <hip/hip_bf16.h>

static constexpr int H = 16;   // hidden channels
static constexpr int C = 16;   // num classes

typedef __attribute__((ext_vector_type(8))) short bf16x8;
typedef __attribute__((ext_vector_type(4))) float f32x4;

static __device__ inline unsigned short f2bf(float x) {
    __hip_bfloat16 b = __float2bfloat16(x);
    return *reinterpret_cast<unsigned short*>(&b);
}
static __device__ inline float bflo(unsigned u) { return __uint_as_float(u << 16); }
static __device__ inline float bfhi(unsigned u) { return __uint_as_float(u & 0xffff0000u); }
// packed bf16 atomic add (2 channels per dword)
static __device__ inline void pk_atomic_bf16(unsigned short* addr, unsigned pk) {
    asm volatile("global_atomic_pk_add_bf16 %0, %1, off" :: "v"(addr), "v"(pk) : "memory");
}

// ---------------- fused prep: zero acc1+acc2 | W2->w2t cast | chunk map ------------
// Thread ranges:  [0, 4N)            zero acc1||acc2 (contiguous, uint4 stores)
//                 [4N, 4N+R*256)     cast W2 -> bf16 transposed [R][C][H]
//                 [.., .. + UB)      chunk c -> (e0, r, n); n=0 for c >= real total
__global__ void k0_fused(const float* __restrict__ W2, const int* __restrict__ ts,
                         unsigned short* __restrict__ w2t, uint4* __restrict__ zbase,
                         int* __restrict__ cmap_e0, int* __restrict__ cmap_rn,
                         int N, int R, int UB) {
    int t = blockIdx.x * blockDim.x + threadIdx.x;
    int nz = 4 * N;
    if (t < nz) {
        zbase[t] = make_uint4(0u, 0u, 0u, 0u);
        return;
    }
    t -= nz;
    if (t < R * 256) {
        int r = t >> 8;
        int kc = t & 255;
        int k = kc >> 4, c = kc & 15;
        w2t[(r << 8) + (c << 4) + k] = f2bf(W2[t]);
        return;
    }
    t -= R * 256;
    if (t >= UB) return;
    // per-thread local scan over R=32 relations (L1-broadcast loads, cheap)
    int cacc = 0, my_e0 = 0, my_rn = 0;
    for (int r = 0; r < R; ++r) {
        int b = ts[2 * r], e = ts[2 * r + 1];
        int nc = (e - b + 15) >> 4;
        if (t >= cacc && t < cacc + nc) {
            int e0 = b + ((t - cacc) << 4);
            my_e0 = e0;
            my_rn = (min(16, e - e0) << 8) | r;
        }
        cacc += nc;
    }
    cmap_e0[t] = my_e0;
    cmap_rn[t] = my_rn;     // 0 (n=0) for invalid chunks -> k3 skips atomics
}

// ---------------- Layer 1: acc1[dst] += bf16x2(W1[et, src]) ------------------------
// 4 lanes per edge-group x 8 edges per thread. All 8 random 64B gathers are issued
// BEFORE any atomic (sched_barrier fence) -> 8 lines in flight per thread.
static __device__ inline void k1_body(const float* __restrict__ W1,
                                      unsigned short* __restrict__ acc1,
                                      const int* s, const int* d, const int* r,
                                      int n, int q, int N) {
    float4 v[8];
#pragma unroll
    for (int i = 0; i < 8; ++i) {
        unsigned off = (((unsigned)(r[i] * N + s[i])) << 4) + (q << 2);
        v[i] = *(const float4*)(W1 + off);
    }
    __builtin_amdgcn_sched_barrier(0);   // pin: all gathers issued before atomics
#pragma unroll
    for (int i = 0; i < 8; ++i) {
        if (i < n) {
            unsigned plo = ((unsigned)f2bf(v[i].y) << 16) | f2bf(v[i].x);
            unsigned phi = ((unsigned)f2bf(v[i].w) << 16) | f2bf(v[i].z);
            unsigned short* base = acc1 + ((size_t)d[i] << 4) + (q << 2);
            pk_atomic_bf16(base, plo);
            pk_atomic_bf16(base + 2, phi);
        }
    }
}

__global__ void k1_scatter(const int* __restrict__ srcv, const int* __restrict__ dstv,
                           const int* __restrict__ etv, const float* __restrict__ W1,
                           unsigned short* __restrict__ acc1, int E, int N) {
    int t = blockIdx.x * blockDim.x + threadIdx.x;
    int g = t >> 2;            // group of 4 lanes handles 8 edges
    int q = t & 3;             // channel quad: channels 4q..4q+3
    int e0 = g << 3;
    if (e0 >= E) return;
    int s[8], d[8], r[8];
    if (e0 + 8 <= E) {
        int4 s0 = *(const int4*)(srcv + e0), s1 = *(const int4*)(srcv + e0 + 4);
        int4 d0 = *(const int4*)(dstv + e0), d1 = *(const int4*)(dstv + e0 + 4);
        int4 r0 = *(const int4*)(etv + e0),  r1 = *(const int4*)(etv + e0 + 4);
        s[0]=s0.x; s[1]=s0.y; s[2]=s0.z; s[3]=s0.w; s[4]=s1.x; s[5]=s1.y; s[6]=s1.z; s[7]=s1.w;
        d[0]=d0.x; d[1]=d0.y; d[2]=d0.z; d[3]=d0.w; d[4]=d1.x; d[5]=d1.y; d[6]=d1.z; d[7]=d1.w;
        r[0]=r0.x; r[1]=r0.y; r[2]=r0.z; r[3]=r0.w; r[4]=r1.x; r[5]=r1.y; r[6]=r1.z; r[7]=r1.w;
        k1_body(W1, acc1, s, d, r, 8, q, N);
    } else {
        int n = E - e0;
#pragma unroll
        for (int i = 0; i < 8; ++i) {
            int e = e0 + ((i < n) ? i : 0);
            s[i] = srcv[e]; d[i] = dstv[e]; r[i] = etv[e];
        }
        k1_body(W1, acc1, s, d, r, n, q, N);
    }
}

// ---------------- h1bf = bf16(relu(root1 + acc1 + bias1)) --------------------------
__global__ void k2_fin1(const float* __restrict__ root1, const float* __restrict__ bias1,
                        const unsigned short* __restrict__ acc1,
                        unsigned int* __restrict__ h1bf, int total4) {
    int i = blockIdx.x * blockDim.x + threadIdx.x;
    if (i >= total4) return;
    float4 rv = ((const float4*)root1)[i];
    uint2 av = ((const uint2*)acc1)[i];
    float4 bv = ((const float4*)bias1)[i & 3];
    float4 o;
    o.x = fmaxf(rv.x + bflo(av.x) + bv.x, 0.0f);
    o.y = fmaxf(rv.y + bfhi(av.x) + bv.y, 0.0f);
    o.z = fmaxf(rv.z + bflo(av.y) + bv.z, 0.0f);
    o.w = fmaxf(rv.w + bfhi(av.y) + bv.w, 0.0f);
    uint2 p;
    p.x = ((unsigned)f2bf(o.y) << 16) | f2bf(o.x);
    p.y = ((unsigned)f2bf(o.w) << 16) | f2bf(o.z);
    ((uint2*)h1bf)[i] = p;
}

// ---------------- Layer 2 via MFMA: one wave = 4 chunks (64 edges) -----------------
// Phase-fenced so all 4 chunks' load chains run concurrently (width-4 MLP).
__global__ void k3_mfma(const int* __restrict__ srcv, const int* __restrict__ dstv,
                        const int* __restrict__ cmap_e0, const int* __restrict__ cmap_rn,
                        const unsigned short* __restrict__ h1bf,
                        const unsigned short* __restrict__ w2t,
                        unsigned short* __restrict__ acc2, int UB) {
    int w = (blockIdx.x * blockDim.x + threadIdx.x) >> 6;
    int l = threadIdx.x & 63;
    int c0 = w << 2;
    if (c0 >= UB) return;
    int rowA = l & 15;
    int kg = l >> 4;

    int e0[4], rr[4], nn[4];
#pragma unroll
    for (int q = 0; q < 4; ++q) {
        int cq = c0 + q;
        bool ok = cq < UB;
        e0[q] = ok ? cmap_e0[cq] : 0;
        int rn = ok ? cmap_rn[cq] : 0;
        rr[q] = rn & 255;
        nn[q] = rn >> 8;            // 0 -> chunk produces no atomics
    }
    __builtin_amdgcn_sched_barrier(0);
    int s[4], dd[4];
#pragma unroll
    for (int q = 0; q < 4; ++q) {
        int eA = e0[q] + max(0, min(rowA, nn[q] - 1));
        s[q] = srcv[eA];
        dd[q] = dstv[eA];           // lane rowA holds row rowA's dst
    }
    __builtin_amdgcn_sched_barrier(0);
    bf16x8 a[4], b[4];
#pragma unroll
    for (int q = 0; q < 4; ++q) {
        bf16x8 z = {0, 0, 0, 0, 0, 0, 0, 0};
        a[q] = z; b[q] = z;
        if (kg < 2) {
            a[q] = *(const bf16x8*)(h1bf + ((size_t)s[q] << 4) + (kg << 3));
            b[q] = *(const bf16x8*)(w2t + ((size_t)rr[q] << 8) + (rowA << 4) + (kg << 3));
        }
    }
    __builtin_amdgcn_sched_barrier(0);
    f32x4 d[4];
#pragma unroll
    for (int q = 0; q < 4; ++q) {
        f32x4 z4 = {0.f, 0.f, 0.f, 0.f};
        d[q] = __builtin_amdgcn_mfma_f32_16x16x32_bf16(a[q], b[q], z4, 0, 0, 0);
    }
    int c = l & 15;
#pragma unroll
    for (int q = 0; q < 4; ++q) {
#pragma unroll
        for (int j = 0; j < 4; ++j) {
            int row = (kg << 2) + j;
            float o = __shfl_xor(d[q][j], 1);          // neighbor column, same row
            int ddv = __shfl(dd[q], row);              // dst of this row
            if (((l & 1) == 0) && row < nn[q]) {
                unsigned pk = ((unsigned)f2bf(o) << 16) | f2bf(d[q][j]);
                pk_atomic_bf16(acc2 + ((size_t)ddv << 4) + c, pk);
            }
        }
    }
}

// ---------------- h2 = h1 @ root2 + acc2 + bias2; row log_softmax ------------------
__global__ void k4_fin2(const unsigned short* __restrict__ h1bf,
                        const unsigned short* __restrict__ acc2,
                        const float* __restrict__ root2, const float* __restrict__ bias2,
                        float* __restrict__ out, int N) {
    int n = blockIdx.x * blockDim.x + threadIdx.x;
    if (n >= N) return;
    const uint4* hp = (const uint4*)(h1bf + (size_t)n * 16);
    uint4 h0 = hp[0], h1 = hp[1];
    float h[16] = {bflo(h0.x), bfhi(h0.x), bflo(h0.y), bfhi(h0.y),
                   bflo(h0.z), bfhi(h0.z), bflo(h0.w), bfhi(h0.w),
                   bflo(h1.x), bfhi(h1.x), bflo(h1.y), bfhi(h1.y),
                   bflo(h1.z), bfhi(h1.z), bflo(h1.w), bfhi(h1.w)};
    const uint4* ap = (const uint4*)(acc2 + (size_t)n * 16);
    uint4 a0 = ap[0], a1 = ap[1];
    float av[16] = {bflo(a0.x), bfhi(a0.x), bflo(a0.y), bfhi(a0.y),
                    bflo(a0.z), bfhi(a0.z), bflo(a0.w), bfhi(a0.w),
                    bflo(a1.x), bfhi(a1.x), bflo(a1.y), bfhi(a1.y),
                    bflo(a1.z), bfhi(a1.z), bflo(a1.w), bfhi(a1.w)};
    float* o = out + (size_t)n * C;
    float z[16];
#pragma unroll
    for (int c = 0; c < 16; ++c) {
        float acc = av[c] + bias2[c];
#pragma unroll
        for (int k = 0; k < 16; ++k) acc += h[k] * root2[k * C + c];
        z[c] = acc;
    }
    float m = z[0];
#pragma unroll
    for (int c = 1; c < 16; ++c) m = fmaxf(m, z[c]);
    float se = 0.f;
#pragma unroll
    for (int c = 0; c < 16; ++c) se += __expf(z[c] - m);
    float lse = m + __logf(se);
#pragma unroll
    for (int c = 0; c < 16; ++c) o[c] = z[c] - lse;
}

extern "C" void kernel_launch(void* const* d_in, const int* in_sizes, int n_in,
                              void* d_out, int out_size, void* d_ws, size_t ws_size,
                              hipStream_t stream) {
    const int*   edge_index   = (const int*)d_in[0];
    const int*   tensor_slice = (const int*)d_in[2];
    const int*   edge_type    = (const int*)d_in[1];
    const float* W1    = (const float*)d_in[3];
    const float* root1 = (const float*)d_in[4];
    const float* bias1 = (const float*)d_in[5];
    const float* W2    = (const float*)d_in[6];
    const float* root2 = (const float*)d_in[7];
    const float* bias2 = (const float*)d_in[8];
    float* out = (float*)d_out;

    const int E = in_sizes[0] / 2;
    const int N = in_sizes[4] / H;           // root1 is N*H
    const int R = in_sizes[2] / 2;           // tensor_slice is [R][2]
    const int* srcv = edge_index;
    const int* dstv = edge_index + E;

    // ws: acc1 bf16[N*16] | acc2 bf16[N*16] (contiguous for fused zeroing)
    //     | h1bf u16[N*16] | w2t u16[R*256] | cmap_e0 int[UB] | cmap_rn int[UB]
    const int UB = (E + 15) / 16 + R;        // upper bound on chunk count
    char* p = (char*)d_ws;
    unsigned short* acc1 = (unsigned short*)p;   p += (size_t)N * 16 * 2;
    unsigned short* acc2 = (unsigned short*)p;   p += (size_t)N * 16 * 2;
    unsigned short* h1bf = (unsigned short*)p;   p += (size_t)N * 16 * 2;
    unsigned short* w2t = (unsigned short*)p;    p += (size_t)R * 256 * 2;
    int* cmap_e0 = (int*)p;                      p += (size_t)UB * 4;
    int* cmap_rn = (int*)p;

    const int B = 256;
    // fused prep: zero both accumulators, cast W2, build chunk map — one launch
    int prep_threads = 4 * N + R * 256 + UB;
    k0_fused<<<(prep_threads + B - 1) / B, B, 0, stream>>>(W2, tensor_slice, w2t,
                                                           (uint4*)acc1, cmap_e0, cmap_rn,
                                                           N, R, UB);
    // layer 1: 4 lanes x 8 edges per group
    long long g1 = ((long long)E + 7) / 8;
    long long t1 = g1 * 4;
    k1_scatter<<<(int)((t1 + B - 1) / B), B, 0, stream>>>(srcv, dstv, edge_type, W1, acc1, E, N);
    int total4 = N * H / 4;
    k2_fin1<<<(total4 + B - 1) / B, B, 0, stream>>>(root1, bias1, acc1,
                                                    (unsigned int*)h1bf, total4);
    // layer 2: 4 chunks per wave
    long long waves = ((long long)UB + 3) / 4;
    long long thr = waves * 64;
    k3_mfma<<<(int)((thr + B - 1) / B), B, 0, stream>>>(srcv, dstv, cmap_e0, cmap_rn,
                                                        h1bf, w2t, acc2, UB);
    k4_fin2<<<(N + B - 1) / B, B, 0, stream>>>(h1bf, acc2, root2, bias2, out, N);
}

// Round 9
// 182.371 us; speedup vs baseline: 1.4463x; 1.4463x over previous
//
#include <hip/hip_runtime.h>
#include <hip/hip_bf16.h>

static constexpr int H = 16;   // hidden channels
static constexpr int C = 16;   // num classes

typedef __attribute__((ext_vector_type(8))) short bf16x8;
typedef __attribute__((ext_vector_type(4))) float f32x4;

static __device__ inline unsigned short f2bf(float x) {
    __hip_bfloat16 b = __float2bfloat16(x);
    return *reinterpret_cast<unsigned short*>(&b);
}
static __device__ inline float bflo(unsigned u) { return __uint_as_float(u << 16); }
static __device__ inline float bfhi(unsigned u) { return __uint_as_float(u & 0xffff0000u); }
// packed bf16 atomic add (2 channels per dword)
static __device__ inline void pk_atomic_bf16(unsigned short* addr, unsigned pk) {
    asm volatile("global_atomic_pk_add_bf16 %0, %1, off" :: "v"(addr), "v"(pk) : "memory");
}
// relu on two packed bf16 (exact, bit ops only)
static __device__ inline unsigned relu_pk2(unsigned u) {
    unsigned lo = (u & 0x8000u) ? 0u : (u & 0x0000ffffu);
    unsigned hi = (u & 0x80000000u) ? 0u : (u & 0xffff0000u);
    return lo | hi;
}

// ---------------- fused prep: acc1=bf16(root1+bias1) | zero acc2 | W2 cast | cmap --
// Thread ranges: [0,4N) init acc1 (uint2) | [4N,6N) zero acc2 (uint4)
//                [6N,6N+R*256) cast W2 -> bf16 transposed [R][C][H]
//                [..,..+UB) chunk c -> (e0, r, n); n=0 for c >= real total
__global__ void k0_fused(const float* __restrict__ W2, const int* __restrict__ ts,
                         const float* __restrict__ root1, const float* __restrict__ bias1,
                         unsigned short* __restrict__ acc1, unsigned short* __restrict__ acc2,
                         unsigned short* __restrict__ w2t,
                         int* __restrict__ cmap_e0, int* __restrict__ cmap_rn,
                         int N, int R, int UB) {
    int t = blockIdx.x * blockDim.x + threadIdx.x;
    if (t < 4 * N) {
        float4 rv = ((const float4*)root1)[t];
        float4 bv = ((const float4*)bias1)[t & 3];
        uint2 p;
        p.x = ((unsigned)f2bf(rv.y + bv.y) << 16) | f2bf(rv.x + bv.x);
        p.y = ((unsigned)f2bf(rv.w + bv.w) << 16) | f2bf(rv.z + bv.z);
        ((uint2*)acc1)[t] = p;
        return;
    }
    t -= 4 * N;
    if (t < 2 * N) {
        ((uint4*)acc2)[t] = make_uint4(0u, 0u, 0u, 0u);
        return;
    }
    t -= 2 * N;
    if (t < R * 256) {
        int r = t >> 8;
        int kc = t & 255;
        int k = kc >> 4, c = kc & 15;
        w2t[(r << 8) + (c << 4) + k] = f2bf(W2[t]);
        return;
    }
    t -= R * 256;
    if (t >= UB) return;
    int cacc = 0, my_e0 = 0, my_rn = 0;
    for (int r = 0; r < R; ++r) {
        int b = ts[2 * r], e = ts[2 * r + 1];
        int nc = (e - b + 15) >> 4;
        if (t >= cacc && t < cacc + nc) {
            int e0 = b + ((t - cacc) << 4);
            my_e0 = e0;
            my_rn = (min(16, e - e0) << 8) | r;
        }
        cacc += nc;
    }
    cmap_e0[t] = my_e0;
    cmap_rn[t] = my_rn;     // n=0 for invalid chunks -> k3 skips their atomics
}

// ---------------- Layer 1: acc1[dst] += bf16x2(W1[et, src]) ------------------------
// Round-7 proven shape: 8 lanes x 8 edges per group, ONE pk atomic per edge per lane
// (one instruction covers the full 32B row via 8 lanes). No sched fences — the
// compiler's load->atomic software pipeline is optimal here (r8 post-mortem).
// XCD-chunked block swizzle: blocks b===x (mod 8) run on XCD x; give them a
// contiguous edge range so the active W1 relation slab (~4MB) fits that XCD's L2.
__global__ void k1_scatter(const int* __restrict__ srcv, const int* __restrict__ dstv,
                           const int* __restrict__ etv, const float* __restrict__ W1,
                           unsigned short* __restrict__ acc1, int E, int N, int nblk8) {
    int b = blockIdx.x;
    int q = nblk8 >> 3;
    int sb = (b & 7) * q + (b >> 3);          // bijective: nblk8 is a multiple of 8
    int t = sb * 256 + (int)threadIdx.x;
    int g = t >> 3;            // group of 8 lanes handles 8 edges
    int cp = t & 7;            // channel pair: channels 2cp, 2cp+1
    int e0 = g << 3;
    if (e0 >= E) return;
    int s[8], d[8], r[8];
    int n;
    if (e0 + 8 <= E) {
        n = 8;
        int4 s0 = *(const int4*)(srcv + e0), s1 = *(const int4*)(srcv + e0 + 4);
        int4 d0 = *(const int4*)(dstv + e0), d1 = *(const int4*)(dstv + e0 + 4);
        int4 r0 = *(const int4*)(etv + e0),  r1 = *(const int4*)(etv + e0 + 4);
        s[0]=s0.x; s[1]=s0.y; s[2]=s0.z; s[3]=s0.w; s[4]=s1.x; s[5]=s1.y; s[6]=s1.z; s[7]=s1.w;
        d[0]=d0.x; d[1]=d0.y; d[2]=d0.z; d[3]=d0.w; d[4]=d1.x; d[5]=d1.y; d[6]=d1.z; d[7]=d1.w;
        r[0]=r0.x; r[1]=r0.y; r[2]=r0.z; r[3]=r0.w; r[4]=r1.x; r[5]=r1.y; r[6]=r1.z; r[7]=r1.w;
    } else {
        n = E - e0;
#pragma unroll
        for (int i = 0; i < 8; ++i) {
            int e = e0 + ((i < n) ? i : 0);
            s[i] = srcv[e]; d[i] = dstv[e]; r[i] = etv[e];
        }
    }
    float2 v[8];
#pragma unroll
    for (int i = 0; i < 8; ++i) {
        unsigned off = ((unsigned)(r[i] * N + s[i]) << 4) + ((unsigned)cp << 1);
        v[i] = *(const float2*)(W1 + off);
    }
#pragma unroll
    for (int i = 0; i < 8; ++i) {
        if (i < n) {
            unsigned pk = ((unsigned)f2bf(v[i].y) << 16) | f2bf(v[i].x);
            pk_atomic_bf16(acc1 + ((size_t)d[i] << 4) + (cp << 1), pk);
        }
    }
}

// ---------------- h1bf = relu(acc1), pure bit-op repack ----------------------------
__global__ void k2_fin1(const uint2* __restrict__ acc1, uint2* __restrict__ h1bf, int total) {
    int i = blockIdx.x * blockDim.x + threadIdx.x;
    if (i >= total) return;
    uint2 a = acc1[i];
    uint2 p;
    p.x = relu_pk2(a.x);
    p.y = relu_pk2(a.y);
    h1bf[i] = p;
}

// ---------------- Layer 2 via MFMA: one wave = 4 chunks (64 edges) -----------------
__global__ void k3_mfma(const int* __restrict__ srcv, const int* __restrict__ dstv,
                        const int* __restrict__ cmap_e0, const int* __restrict__ cmap_rn,
                        const unsigned short* __restrict__ h1bf,
                        const unsigned short* __restrict__ w2t,
                        unsigned short* __restrict__ acc2, int UB) {
    int w = (blockIdx.x * blockDim.x + threadIdx.x) >> 6;
    int l = threadIdx.x & 63;
    int c0 = w << 2;
    if (c0 >= UB) return;
    int rowA = l & 15;
    int kg = l >> 4;

    int e0[4], rr[4], nn[4];
#pragma unroll
    for (int q = 0; q < 4; ++q) {
        int cq = c0 + q;
        bool ok = cq < UB;
        e0[q] = ok ? cmap_e0[cq] : 0;
        int rn = ok ? cmap_rn[cq] : 0;
        rr[q] = rn & 255;
        nn[q] = rn >> 8;            // 0 -> chunk produces no atomics
    }
    __builtin_amdgcn_sched_barrier(0);
    int s[4], dd[4];
#pragma unroll
    for (int q = 0; q < 4; ++q) {
        int eA = e0[q] + max(0, min(rowA, nn[q] - 1));
        s[q] = srcv[eA];
        dd[q] = dstv[eA];           // lane rowA holds row rowA's dst
    }
    __builtin_amdgcn_sched_barrier(0);
    bf16x8 a[4], b[4];
#pragma unroll
    for (int q = 0; q < 4; ++q) {
        bf16x8 z = {0, 0, 0, 0, 0, 0, 0, 0};
        a[q] = z; b[q] = z;
        if (kg < 2) {
            a[q] = *(const bf16x8*)(h1bf + ((size_t)s[q] << 4) + (kg << 3));
            b[q] = *(const bf16x8*)(w2t + ((size_t)rr[q] << 8) + (rowA << 4) + (kg << 3));
        }
    }
    __builtin_amdgcn_sched_barrier(0);
    f32x4 d[4];
#pragma unroll
    for (int q = 0; q < 4; ++q) {
        f32x4 z4 = {0.f, 0.f, 0.f, 0.f};
        d[q] = __builtin_amdgcn_mfma_f32_16x16x32_bf16(a[q], b[q], z4, 0, 0, 0);
    }
    int c = l & 15;
#pragma unroll
    for (int q = 0; q < 4; ++q) {
#pragma unroll
        for (int j = 0; j < 4; ++j) {
            int row = (kg << 2) + j;
            float o = __shfl_xor(d[q][j], 1);          // neighbor column, same row
            int ddv = __shfl(dd[q], row);              // dst of this row
            if (((l & 1) == 0) && row < nn[q]) {
                unsigned pk = ((unsigned)f2bf(o) << 16) | f2bf(d[q][j]);
                pk_atomic_bf16(acc2 + ((size_t)ddv << 4) + c, pk);
            }
        }
    }
}

// ---------------- h2 = h1 @ root2 + acc2 + bias2; row log_softmax ------------------
__global__ void k4_fin2(const unsigned short* __restrict__ h1bf,
                        const unsigned short* __restrict__ acc2,
                        const float* __restrict__ root2, const float* __restrict__ bias2,
                        float* __restrict__ out, int N) {
    int n = blockIdx.x * blockDim.x + threadIdx.x;
    if (n >= N) return;
    const uint4* hp = (const uint4*)(h1bf + (size_t)n * 16);
    uint4 h0 = hp[0], h1 = hp[1];
    float h[16] = {bflo(h0.x), bfhi(h0.x), bflo(h0.y), bfhi(h0.y),
                   bflo(h0.z), bfhi(h0.z), bflo(h0.w), bfhi(h0.w),
                   bflo(h1.x), bfhi(h1.x), bflo(h1.y), bfhi(h1.y),
                   bflo(h1.z), bfhi(h1.z), bflo(h1.w), bfhi(h1.w)};
    const uint4* ap = (const uint4*)(acc2 + (size_t)n * 16);
    uint4 a0 = ap[0], a1 = ap[1];
    float av[16] = {bflo(a0.x), bfhi(a0.x), bflo(a0.y), bfhi(a0.y),
                    bflo(a0.z), bfhi(a0.z), bflo(a0.w), bfhi(a0.w),
                    bflo(a1.x), bfhi(a1.x), bflo(a1.y), bfhi(a1.y),
                    bflo(a1.z), bfhi(a1.z), bflo(a1.w), bfhi(a1.w)};
    float* o = out + (size_t)n * C;
    float z[16];
#pragma unroll
    for (int c = 0; c < 16; ++c) {
        float acc = av[c] + bias2[c];
#pragma unroll
        for (int k = 0; k < 16; ++k) acc += h[k] * root2[k * C + c];
        z[c] = acc;
    }
    float m = z[0];
#pragma unroll
    for (int c = 1; c < 16; ++c) m = fmaxf(m, z[c]);
    float se = 0.f;
#pragma unroll
    for (int c = 0; c < 16; ++c) se += __expf(z[c] - m);
    float lse = m + __logf(se);
#pragma unroll
    for (int c = 0; c < 16; ++c) o[c] = z[c] - lse;
}

extern "C" void kernel_launch(void* const* d_in, const int* in_sizes, int n_in,
                              void* d_out, int out_size, void* d_ws, size_t ws_size,
                              hipStream_t stream) {
    const int*   edge_index   = (const int*)d_in[0];
    const int*   edge_type    = (const int*)d_in[1];
    const int*   tensor_slice = (const int*)d_in[2];
    const float* W1    = (const float*)d_in[3];
    const float* root1 = (const float*)d_in[4];
    const float* bias1 = (const float*)d_in[5];
    const float* W2    = (const float*)d_in[6];
    const float* root2 = (const float*)d_in[7];
    const float* bias2 = (const float*)d_in[8];
    float* out = (float*)d_out;

    const int E = in_sizes[0] / 2;
    const int N = in_sizes[4] / H;           // root1 is N*H
    const int R = in_sizes[2] / 2;           // tensor_slice is [R][2]
    const int* srcv = edge_index;
    const int* dstv = edge_index + E;

    // ws: acc1 bf16[N*16] | acc2 bf16[N*16] | h1bf u16[N*16] | w2t u16[R*256]
    //     | cmap_e0 int[UB] | cmap_rn int[UB]
    const int UB = (E + 15) / 16 + R;        // upper bound on chunk count
    char* p = (char*)d_ws;
    unsigned short* acc1 = (unsigned short*)p;   p += (size_t)N * 16 * 2;
    unsigned short* acc2 = (unsigned short*)p;   p += (size_t)N * 16 * 2;
    unsigned short* h1bf = (unsigned short*)p;   p += (size_t)N * 16 * 2;
    unsigned short* w2t = (unsigned short*)p;    p += (size_t)R * 256 * 2;
    int* cmap_e0 = (int*)p;                      p += (size_t)UB * 4;
    int* cmap_rn = (int*)p;

    const int B = 256;
    // fused prep: init acc1 with root1+bias1, zero acc2, cast W2, build chunk map
    int prep_threads = 6 * N + R * 256 + UB;
    k0_fused<<<(prep_threads + B - 1) / B, B, 0, stream>>>(W2, tensor_slice, root1, bias1,
                                                           acc1, acc2, w2t,
                                                           cmap_e0, cmap_rn, N, R, UB);
    // layer 1: 8 lanes x 8 edges per group, XCD-chunked swizzle (grid padded to x8)
    long long t1 = (((long long)E + 7) / 8) * 8;
    int nblk1 = (int)((t1 + B - 1) / B);
    nblk1 = (nblk1 + 7) & ~7;
    k1_scatter<<<nblk1, B, 0, stream>>>(srcv, dstv, edge_type, W1, acc1, E, N, nblk1);
    // relu repack
    k2_fin1<<<(4 * N + B - 1) / B, B, 0, stream>>>((const uint2*)acc1, (uint2*)h1bf, 4 * N);
    // layer 2: 4 chunks per wave
    long long waves = ((long long)UB + 3) / 4;
    long long thr = waves * 64;
    k3_mfma<<<(int)((thr + B - 1) / B), B, 0, stream>>>(srcv, dstv, cmap_e0, cmap_rn,
                                                        h1bf, w2t, acc2, UB);
    k4_fin2<<<(N + B - 1) / B, B, 0, stream>>>(h1bf, acc2, root2, bias2, out, N);
}